// Round 6
// baseline (345.336 us; speedup 1.0000x reference)
//
#include <hip/hip_runtime.h>
#include <cstdint>

#define NEG (-1e12f)
constexpr int Bn = 32, Ln = 256, Tn = 2048;
constexpr int TB = Tn / 64;                 // 32 uint64 words of t-bits per text row
constexpr int WST_BSTRIDE = (Tn - 1) * Ln;  // 524032 floats per batch in wsT
constexpr int WST_OFF = 8192;               // wsT = out + 8192 (out[0..8191] untouched by scratch)

// d_ws layout (bytes):
//   bits    @ 0       : 32*256*32*8 = 2,097,152
//   partial @ 2097152 : 1024 floats (4 KB)
//   ext     @ 2101248 : 8192 int2  (64 KB)
//   flags   @ 2166784 : int[1025]  (cnt[b][tt] = [32][32], ticket at [1024])

__device__ inline void gl_lds16(const float* g, float* l) {
    __builtin_amdgcn_global_load_lds(
        (const __attribute__((address_space(1))) unsigned int*)(g),
        (__attribute__((address_space(3))) unsigned int*)(l),
        16, 0, 0);
}

// lane i <- lane (i-1)&63  (wave_ror:1) : torch-wrap neighbor for the bit compare
__device__ inline float dpp_ror1(float x) {
    int xi = __float_as_int(x);
    return __int_as_float(__builtin_amdgcn_update_dpp(xi, xi, 0x13C, 0xF, 0xF, false));
}
// lane i <- lane i-1, lane 0 <- old  (wave_shr:1) : DP 'left' input directly
__device__ inline float dpp_shr1(float x, float old) {
    return __int_as_float(__builtin_amdgcn_update_dpp(
        __float_as_int(old), __float_as_int(x), 0x138, 0xF, 0xF, false));
}

#define WAITV(N) { asm volatile("s_waitcnt vmcnt(" #N ")" ::: "memory"); \
                   __builtin_amdgcn_sched_barrier(0); }

// wait until all 4 lt-quarters of transpose group TT for this batch are published
#define SPIN(TT) { \
    const int* cp_ = cnt + (TT); \
    while (__hip_atomic_load(cp_, __ATOMIC_RELAXED, __HIP_MEMORY_SCOPE_AGENT) < 4) {} \
    (void)__hip_atomic_load(cp_, __ATOMIC_ACQUIRE, __HIP_MEMORY_SCOPE_AGENT); }

// chunk c covers t = 16c+1 .. 16c+16 ; wsT row (t-1) = 16c+j ; LDS buffer = c & 3
#define ISSUE(C) { \
    const float* gsrc = wbase + (size_t)(C) * 4096 + (lane << 2); \
    float* ldst = buf + ((C) & 3) * 4096; \
    _Pragma("unroll") \
    for (int j = 0; j < 16; ++j) gl_lds16(gsrc + j * 256, ldst + j * 256); }

#define LDQB(BI, ROW) (*reinterpret_cast<const float4*>(buf + (BI) * 4096 + (ROW) * 256 + (lane << 2)))

// S = t - 64m (1..64) compile-time; Q = preloaded float4 for this step
#define STEPS(S, Q) { \
    float c3 = fmaxf(pv3, pv2) + (Q).w; \
    float c2 = fmaxf(pv2, pv1) + (Q).z; \
    float c1 = fmaxf(pv1, pv0) + (Q).y; \
    float c0 = fmaxf(pv0, left) + (Q).x; \
    float sv = dpp_ror1(c3); \
    left = dpp_shr1(c3, negc); \
    uint32_t e0 = __float_as_uint(c0 - sv) >> 31; \
    uint32_t e1 = __float_as_uint(c1 - c0) >> 31; \
    uint32_t e2 = __float_as_uint(c2 - c1) >> 31; \
    uint32_t e3 = __float_as_uint(c3 - c2) >> 31; \
    if (((S) & 32) == 0) { \
        a0lo |= e0 << ((S) & 31); a1lo |= e1 << ((S) & 31); \
        a2lo |= e2 << ((S) & 31); a3lo |= e3 << ((S) & 31); \
    } else { \
        a0hi |= e0 << ((S) & 31); a1hi |= e1 << ((S) & 31); \
        a2hi |= e2 << ((S) & 31); a3hi |= e3 << ((S) & 31); \
    } \
    if ((S) == 63) { \
        bb[(size_t)(4 * lane + 0) * TB + m] = ((uint64_t)a0hi << 32) | a0lo; \
        bb[(size_t)(4 * lane + 1) * TB + m] = ((uint64_t)a1hi << 32) | a1lo; \
        bb[(size_t)(4 * lane + 2) * TB + m] = ((uint64_t)a2hi << 32) | a2lo; \
        bb[(size_t)(4 * lane + 3) * TB + m] = ((uint64_t)a3hi << 32) | a3lo; \
        a0lo = a0hi = a1lo = a1hi = a2lo = a2hi = a3lo = a3hi = 0; \
    } \
    pv0 = c0; pv1 = c1; pv2 = c2; pv3 = c3; }

// 16 steps of sub-chunk I (chunk c = 4m+I, buffer I); 8-deep rotating prefetch
#define COMP16(I) { \
    STEPS(16*(I)+ 1, qq0) qq0 = LDQB((I), 8); \
    STEPS(16*(I)+ 2, qq1) qq1 = LDQB((I), 9); \
    STEPS(16*(I)+ 3, qq2) qq2 = LDQB((I),10); \
    STEPS(16*(I)+ 4, qq3) qq3 = LDQB((I),11); \
    STEPS(16*(I)+ 5, qq4) qq4 = LDQB((I),12); \
    STEPS(16*(I)+ 6, qq5) qq5 = LDQB((I),13); \
    STEPS(16*(I)+ 7, qq6) qq6 = LDQB((I),14); \
    STEPS(16*(I)+ 8, qq7) qq7 = LDQB((I),15); \
    STEPS(16*(I)+ 9, qq0) qq0 = LDQB(((I)+1)&3, 0); \
    STEPS(16*(I)+10, qq1) qq1 = LDQB(((I)+1)&3, 1); \
    STEPS(16*(I)+11, qq2) qq2 = LDQB(((I)+1)&3, 2); \
    STEPS(16*(I)+12, qq3) qq3 = LDQB(((I)+1)&3, 3); \
    STEPS(16*(I)+13, qq4) qq4 = LDQB(((I)+1)&3, 4); \
    STEPS(16*(I)+14, qq5) qq5 = LDQB(((I)+1)&3, 5); \
    STEPS(16*(I)+15, qq6) qq6 = LDQB(((I)+1)&3, 6); \
    STEPS(16*(I)+16, qq7) qq7 = LDQB(((I)+1)&3, 7); }

// ============ mega kernel: forward (0..31) | transpose (32..4127) | loss (4128..5151) ============
__global__ void __launch_bounds__(256, 1) k_mega(
        const float* __restrict__ logp, const float* __restrict__ att,
        const int* __restrict__ ilen, const int* __restrict__ olen,
        float* __restrict__ out, uint64_t* __restrict__ bits,
        float* __restrict__ partial, int* __restrict__ flags) {
    __shared__ __align__(16) float smem[16384];   // 64 KB (staging ring / transpose tile / reduce)
    int bid = blockIdx.x, tid = threadIdx.x;
    float* wsT = out + WST_OFF;

    if (bid < 32) {
        // ---------------- forward DP (one wave per batch) ----------------
        if (tid >= 64) return;
        int b = bid;
        int lane = tid;
        uint64_t* bb = bits + (size_t)b * (Ln * TB);
        const float* wbase = wsT + (size_t)b * WST_BSTRIDE;
        float* buf = smem;
        const int* cnt = flags + b * 32;
        const float negc = NEG;

        float pv0, pv1, pv2, pv3, left;
        uint32_t a0lo = 0, a0hi = 0, a1lo = 0, a1hi = 0;
        uint32_t a2lo = 0, a2hi = 0, a3lo = 0, a3hi = 0;

        // peeled t = 0: row0 = logp[b,0,0], others NEG; seed bit 0 of word 0
        {
            float lp00 = logp[(size_t)b * (Ln * Tn)];
            float n0 = (lane == 0) ? lp00 : NEG;
            float n1 = NEG, n2 = NEG, n3 = NEG;
            float sv = dpp_ror1(n3);
            a0lo |= __float_as_uint(n0 - sv) >> 31;
            a1lo |= __float_as_uint(n1 - n0) >> 31;
            a2lo |= __float_as_uint(n2 - n1) >> 31;
            a3lo |= __float_as_uint(n3 - n2) >> 31;
            left = NEG;
            pv0 = n0; pv1 = n1; pv2 = n2; pv3 = n3;
        }

        SPIN(0)
        ISSUE(0) ISSUE(1) ISSUE(2)        // 48 loads in flight (all tt=0)
        WAITV(16)                          // chunks 0,1 landed; chunk 2 outstanding

        float4 qq0 = LDQB(0, 0), qq1 = LDQB(0, 1), qq2 = LDQB(0, 2), qq3 = LDQB(0, 3);
        float4 qq4 = LDQB(0, 4), qq5 = LDQB(0, 5), qq6 = LDQB(0, 6), qq7 = LDQB(0, 7);

        // invariant at head of sub-chunk c: chunks <= c+1 landed, chunk c+2 in flight
        for (int m = 0; m < 31; ++m) {
            int cb = 4 * m;
            ISSUE(cb + 3) COMP16(0) WAITV(16)
            SPIN(m + 1)                    // tt=m+1 produced? (chunks 4m+4 .. 4m+7)
            ISSUE(cb + 4) COMP16(1) WAITV(16)
            ISSUE(cb + 5) COMP16(2) WAITV(16)
            ISSUE(cb + 6) COMP16(3) WAITV(16)
        }
        {   // m = 31: chunks 124..127 (tt=31 already spun at m=30)
            int m = 31;
            ISSUE(127) COMP16(0) WAITV(16)
            COMP16(1) WAITV(0)             // drain chunk 127 before its rows are prefetched
            COMP16(2)
            COMP16(3)                      // j>=8 prefetches read stale buffer 0: never consumed
        }
    } else if (bid < 32 + 4096) {
        // ---------------- transpose logp[b][l][t] -> wsT[b][t-1][l], tt-major order ----------------
        int bid2 = bid - 32;
        int tt = bid2 >> 7;                // early blocks produce early t: forward unblocks fast
        int rest = bid2 & 127;
        int b = rest >> 2;
        int lt = rest & 3;
        float* tile = smem;                // [64][68]
        const float* src = logp + ((size_t)b * Ln + lt * 64) * Tn + (size_t)tt * 64;
        int lr = tid >> 4, tc4 = (tid & 15) * 4;
        #pragma unroll
        for (int pass = 0; pass < 4; ++pass) {
            int l_loc = pass * 16 + lr;
            float4 v = *(const float4*)(src + (size_t)l_loc * Tn + tc4);
            *(float4*)(&tile[l_loc * 68 + tc4]) = v;
        }
        __syncthreads();
        float* dst = wsT + (size_t)b * WST_BSTRIDE + lt * 64;
        #pragma unroll
        for (int pass = 0; pass < 4; ++pass) {
            int t_loc = pass * 16 + lr;
            float4 v;
            v.x = tile[(tc4 + 0) * 68 + t_loc];
            v.y = tile[(tc4 + 1) * 68 + t_loc];
            v.z = tile[(tc4 + 2) * 68 + t_loc];
            v.w = tile[(tc4 + 3) * 68 + t_loc];
            int tg = tt * 64 + t_loc;
            if (tg >= 1) *(float4*)(dst + (size_t)(tg - 1) * Ln + tc4) = v;
        }
        __syncthreads();                   // drains vmcnt: all this block's stores are in L2
        if (tid == 0)                      // release: writeback + publish
            __hip_atomic_fetch_add(&flags[b * 32 + tt], 1,
                                   __ATOMIC_RELEASE, __HIP_MEMORY_SCOPE_AGENT);
    } else {
        // ---------------- guided-attention loss partial + ticketed final reduce ----------------
        const int N4 = Bn * Tn * Ln / 4;
        int j = bid - 4128;
        int idx = j * 256 + tid;
        int stride = 1024 * 256;
        float acc = 0.f;
        for (int v = idx; v < N4; v += stride) {
            int flat = v << 2;                   // att is (B, T, L)
            int b  = flat >> 19;
            int t  = (flat >> 8) & (Tn - 1);
            int l0 = flat & (Ln - 1);
            int ili = ilen[b];
            int oli = olen[b];
            if (t >= oli) continue;
            float il = (float)ili, ol = (float)oli;
            float tf = (float)t / ol;
            float4 a = reinterpret_cast<const float4*>(att)[v];
            #pragma unroll
            for (int c = 0; c < 4; ++c) {
                int l = l0 + c;
                float av = (c == 0) ? a.x : (c == 1) ? a.y : (c == 2) ? a.z : a.w;
                if (l < ili) {
                    float d = (float)l / il - tf;
                    acc += (1.f - __expf(-d * d * 3.125f)) * av;
                }
            }
        }
        for (int off = 32; off > 0; off >>= 1) acc += __shfl_down(acc, off, 64);
        float* sw = smem;                        // [0..3]
        if ((tid & 63) == 0) sw[tid >> 6] = acc;
        __syncthreads();
        if (tid == 0) partial[j] = (sw[0] + sw[1]) + (sw[2] + sw[3]);
        __syncthreads();
        int* si = (int*)smem;
        if (tid == 0)
            si[16] = __hip_atomic_fetch_add(&flags[1024], 1,
                                            __ATOMIC_ACQ_REL, __HIP_MEMORY_SCOPE_AGENT);
        __syncthreads();
        if (si[16] == 1023) {                    // last finisher: deterministic final reduce
            float acc2 = 0.f;
            for (int i = tid; i < 1024; i += 256) acc2 += partial[i];
            for (int off = 32; off > 0; off >>= 1) acc2 += __shfl_down(acc2, off, 64);
            if ((tid & 63) == 0) sw[tid >> 6] = acc2;
            __syncthreads();
            if (tid == 0) {
                float tot = (sw[0] + sw[1]) + (sw[2] + sw[3]);
                int so = 0;
                for (int i = 0; i < Bn; ++i) so += olen[i];
                out[0] = tot / (float)so;
            }
        }
    }
}

// ---------------- backtrack: LDS bits, 4-deep window walk -> per-row extents ----------------
__global__ void __launch_bounds__(64) k_backtrack3(const uint64_t* __restrict__ bits,
                                                   const int* __restrict__ ilen,
                                                   const int* __restrict__ olen,
                                                   int2* __restrict__ ext) {
    __shared__ uint64_t sb[Ln * TB];   // 64 KB
    int b = blockIdx.x, lane = threadIdx.x;
    #pragma unroll
    for (int i = 0; i < 4; ++i) ext[b * Ln + i * 64 + lane] = make_int2(1, 0);  // empty
    const ulonglong2* g = (const ulonglong2*)(bits + (size_t)b * (Ln * TB));
    ulonglong2* s2 = (ulonglong2*)sb;
    #pragma unroll
    for (int i = 0; i < 64; ++i) s2[i * 64 + lane] = g[i * 64 + lane];
    __syncthreads();
    if (lane != 0) return;

    int tl = ilen[b], ml = olen[b];
    int2* eb = ext + b * Ln;
    int r = tl - 1, hi = ml - 1, p = ml - 2;
    if (p < 0) { eb[r] = make_int2(0, hi); return; }
    int c = p >> 6;
    uint64_t w0 = sb[r * TB + c];
    uint64_t w1 = sb[(r > 0 ? r - 1 : 0) * TB + c];
    uint64_t w2 = sb[(r > 1 ? r - 2 : 0) * TB + c];
    uint64_t w3 = sb[(r > 2 ? r - 3 : 0) * TB + c];
    int vd = 3;
    while (true) {
        int pb = p & 63;
        uint64_t mask = (pb == 63) ? ~0ull : ((1ull << (pb + 1)) - 1ull);
        uint64_t m = w0 & mask;
        if (m == 0) {
            p = (p & ~63) - 1;
            if (p < 0) { eb[r] = make_int2(0, hi); break; }
            c = p >> 6;
            w0 = sb[r * TB + c];
            w1 = sb[(r > 0 ? r - 1 : 0) * TB + c];
            w2 = sb[(r > 1 ? r - 2 : 0) * TB + c];
            w3 = sb[(r > 2 ? r - 3 : 0) * TB + c];
            vd = 3;
        } else {
            int q = 63 - __builtin_clzll(m);
            int tq = (p & ~63) + q;
            eb[r] = make_int2(tq + 1, hi);
            r -= 1;
            if (r < 0) break;                   // saturation: remaining columns zero
            hi = tq;
            p = tq - 1;
            if (p < 0) { eb[r] = make_int2(0, hi); break; }
            w0 = w1; w1 = w2; w2 = w3; vd -= 1;
            int nc = p >> 6;
            if (nc != c || vd == 0) {
                c = nc;
                w0 = sb[r * TB + c];
                w1 = sb[(r > 0 ? r - 1 : 0) * TB + c];
                w2 = sb[(r > 1 ? r - 2 : 0) * TB + c];
                w3 = sb[(r > 2 ? r - 3 : 0) * TB + c];
                vd = 3;
            }
        }
    }
}

// ---------------- aligned-float4 fill of the whole align output from extents ----------------
__global__ void k_fill(const int2* __restrict__ ext, float* __restrict__ out) {
    const int NG = (Bn * Ln * Tn) / 4;          // 4,194,304 aligned float4 groups
    int idx = blockIdx.x * blockDim.x + threadIdx.x;
    int stride = gridDim.x * blockDim.x;
    for (int i = idx; i < NG; i += stride) {
        if (i == 0) {
            int2 e = ext[0];                     // out[1..3] = align f=0..2 (row 0)
            out[1] = (0 >= e.x && 0 <= e.y) ? 1.f : 0.f;
            out[2] = (1 >= e.x && 1 <= e.y) ? 1.f : 0.f;
            out[3] = (2 >= e.x && 2 <= e.y) ? 1.f : 0.f;
            int2 el = ext[Bn * Ln - 1];          // last element: row 8191, t=2047
            out[(size_t)Bn * Ln * Tn] = (2047 >= el.x && 2047 <= el.y) ? 1.f : 0.f;
            continue;
        }
        int f0 = 4 * i - 1;                      // align flat index of out[4i]
        int r0 = f0 >> 11;
        int t0 = f0 & 2047;
        int2 e0 = ext[r0];
        float4 v;
        if (t0 != 2047) {                        // all 4 in row r0
            v.x = (t0     >= e0.x && t0     <= e0.y) ? 1.f : 0.f;
            v.y = (t0 + 1 >= e0.x && t0 + 1 <= e0.y) ? 1.f : 0.f;
            v.z = (t0 + 2 >= e0.x && t0 + 2 <= e0.y) ? 1.f : 0.f;
            v.w = (t0 + 3 >= e0.x && t0 + 3 <= e0.y) ? 1.f : 0.f;
        } else {                                 // crosses into row r0+1 (t=0,1,2)
            int2 e1 = ext[r0 + 1];
            v.x = (2047 >= e0.x && 2047 <= e0.y) ? 1.f : 0.f;
            v.y = (0 >= e1.x && 0 <= e1.y) ? 1.f : 0.f;
            v.z = (1 >= e1.x && 1 <= e1.y) ? 1.f : 0.f;
            v.w = (2 >= e1.x && 2 <= e1.y) ? 1.f : 0.f;
        }
        *reinterpret_cast<float4*>(out + (size_t)4 * i) = v;
    }
}

extern "C" void kernel_launch(void* const* d_in, const int* in_sizes, int n_in,
                              void* d_out, int out_size, void* d_ws, size_t ws_size,
                              hipStream_t stream) {
    const float* logp = (const float*)d_in[0];
    const float* att  = (const float*)d_in[1];
    const int* tlen   = (const int*)d_in[2];
    const int* mlen   = (const int*)d_in[3];
    float* out = (float*)d_out;
    uint64_t* bits = (uint64_t*)d_ws;                            // 2 MB
    float* partial = (float*)((char*)d_ws + 2097152);            // 4 KB
    int2* ext = (int2*)((char*)d_ws + 2101248);                  // 64 KB
    int* flags = (int*)((char*)d_ws + 2166784);                  // 1025 ints

    // 0) zero the producer/consumer flags + loss ticket (graph-capture legal)
    hipMemsetAsync(flags, 0, 1025 * sizeof(int), stream);
    // 1) mega kernel: forward DP overlapped with transpose producers + loss
    k_mega<<<5152, 256, 0, stream>>>(logp, att, tlen, mlen, out, bits, partial, flags);
    // 2) backtrack -> per-row run extents
    k_backtrack3<<<Bn, 64, 0, stream>>>(bits, tlen, mlen, ext);
    // 3) write full 0/1 output from extents (overwrites wsT scratch region)
    k_fill<<<2048, 256, 0, stream>>>(ext, out);
}

// Round 7
// 316.693 us; speedup vs baseline: 1.0904x; 1.0904x over previous
//
#include <hip/hip_runtime.h>
#include <cstdint>

#define NEG (-1e12f)
constexpr int Bn = 32, Ln = 256, Tn = 2048;
constexpr int TB = Tn / 64;                 // 32 uint64 words of t-bits per text row
constexpr int WST_BSTRIDE = (Tn - 1) * Ln;  // 524032 floats per batch in wsT
constexpr int WST_OFF = 8192;               // wsT = out + 8192

// d_ws layout (bytes):
//   bits    @ 0       : 32*256*32*8 = 2,097,152
//   partial @ 2097152 : 1024 floats (4 KB)
//   ext     @ 2101248 : 8192 int2  (64 KB)
//   flags   @ 2166784 : int[1024]  (cnt[b][tt] = [32][32])

__device__ inline void gl_lds16(const float* g, float* l) {
    __builtin_amdgcn_global_load_lds(
        (const __attribute__((address_space(1))) unsigned int*)(g),
        (__attribute__((address_space(3))) unsigned int*)(l),
        16, 0, 0);
}

// lane i <- lane (i-1)&63  (wave_ror:1) : torch-wrap neighbor for the bit compare
__device__ inline float dpp_ror1(float x) {
    int xi = __float_as_int(x);
    return __int_as_float(__builtin_amdgcn_update_dpp(xi, xi, 0x13C, 0xF, 0xF, false));
}
// lane i <- lane i-1, lane 0 <- old  (wave_shr:1) : DP 'left' input directly
__device__ inline float dpp_shr1(float x, float old) {
    return __int_as_float(__builtin_amdgcn_update_dpp(
        __float_as_int(old), __float_as_int(x), 0x138, 0xF, 0xF, false));
}

#define WAITV(N) { asm volatile("s_waitcnt vmcnt(" #N ")" ::: "memory"); \
                   __builtin_amdgcn_sched_barrier(0); }

// non-draining flag prefetch: raw load, cache-bypass, retired by the existing WAITV(16)
#define FLAGLOAD(T, DST) { const int* fp_ = cnt + (T); \
    asm volatile("global_load_dword %0, %1, off sc0 sc1" \
                 : "=&v"(DST) : "v"(fp_) : "memory"); }

// rare slow path: self-contained asm spin (drains vmcnt, acceptable here)
#define SLOWSPIN(PTR) { unsigned int t_; const int* sp_ = (PTR); \
    asm volatile("1:\n\t" \
                 "s_sleep 8\n\t" \
                 "global_load_dword %0, %1, off sc0 sc1\n\t" \
                 "s_waitcnt vmcnt(0)\n\t" \
                 "v_cmp_gt_i32 vcc, 4, %0\n\t" \
                 "s_cbranch_vccnz 1b" \
                 : "=&v"(t_) : "v"(sp_) : "vcc", "memory"); }

// chunk c covers t = 16c+1 .. 16c+16 ; wsT row (t-1) = 16c+j ; LDS buffer = c & 3
#define ISSUE(C) { \
    const float* gsrc = wbase + (size_t)(C) * 4096 + (lane << 2); \
    float* ldst = buf + ((C) & 3) * 4096; \
    _Pragma("unroll") \
    for (int j = 0; j < 16; ++j) gl_lds16(gsrc + j * 256, ldst + j * 256); }

#define LDQB(BI, ROW) (*reinterpret_cast<const float4*>(buf + (BI) * 4096 + (ROW) * 256 + (lane << 2)))

// S = t - 64m (1..64) compile-time; Q = preloaded float4 for this step
#define STEPS(S, Q) { \
    float c3 = fmaxf(pv3, pv2) + (Q).w; \
    float c2 = fmaxf(pv2, pv1) + (Q).z; \
    float c1 = fmaxf(pv1, pv0) + (Q).y; \
    float c0 = fmaxf(pv0, left) + (Q).x; \
    float sv = dpp_ror1(c3); \
    left = dpp_shr1(c3, negc); \
    uint32_t e0 = __float_as_uint(c0 - sv) >> 31; \
    uint32_t e1 = __float_as_uint(c1 - c0) >> 31; \
    uint32_t e2 = __float_as_uint(c2 - c1) >> 31; \
    uint32_t e3 = __float_as_uint(c3 - c2) >> 31; \
    if (((S) & 32) == 0) { \
        a0lo |= e0 << ((S) & 31); a1lo |= e1 << ((S) & 31); \
        a2lo |= e2 << ((S) & 31); a3lo |= e3 << ((S) & 31); \
    } else { \
        a0hi |= e0 << ((S) & 31); a1hi |= e1 << ((S) & 31); \
        a2hi |= e2 << ((S) & 31); a3hi |= e3 << ((S) & 31); \
    } \
    if ((S) == 63) { \
        bb[(size_t)(4 * lane + 0) * TB + m] = ((uint64_t)a0hi << 32) | a0lo; \
        bb[(size_t)(4 * lane + 1) * TB + m] = ((uint64_t)a1hi << 32) | a1lo; \
        bb[(size_t)(4 * lane + 2) * TB + m] = ((uint64_t)a2hi << 32) | a2lo; \
        bb[(size_t)(4 * lane + 3) * TB + m] = ((uint64_t)a3hi << 32) | a3lo; \
        a0lo = a0hi = a1lo = a1hi = a2lo = a2hi = a3lo = a3hi = 0; \
    } \
    pv0 = c0; pv1 = c1; pv2 = c2; pv3 = c3; }

// 16 steps of sub-chunk I (chunk c = 4m+I, buffer I); 8-deep rotating prefetch
#define COMP16(I) { \
    STEPS(16*(I)+ 1, qq0) qq0 = LDQB((I), 8); \
    STEPS(16*(I)+ 2, qq1) qq1 = LDQB((I), 9); \
    STEPS(16*(I)+ 3, qq2) qq2 = LDQB((I),10); \
    STEPS(16*(I)+ 4, qq3) qq3 = LDQB((I),11); \
    STEPS(16*(I)+ 5, qq4) qq4 = LDQB((I),12); \
    STEPS(16*(I)+ 6, qq5) qq5 = LDQB((I),13); \
    STEPS(16*(I)+ 7, qq6) qq6 = LDQB((I),14); \
    STEPS(16*(I)+ 8, qq7) qq7 = LDQB((I),15); \
    STEPS(16*(I)+ 9, qq0) qq0 = LDQB(((I)+1)&3, 0); \
    STEPS(16*(I)+10, qq1) qq1 = LDQB(((I)+1)&3, 1); \
    STEPS(16*(I)+11, qq2) qq2 = LDQB(((I)+1)&3, 2); \
    STEPS(16*(I)+12, qq3) qq3 = LDQB(((I)+1)&3, 3); \
    STEPS(16*(I)+13, qq4) qq4 = LDQB(((I)+1)&3, 4); \
    STEPS(16*(I)+14, qq5) qq5 = LDQB(((I)+1)&3, 5); \
    STEPS(16*(I)+15, qq6) qq6 = LDQB(((I)+1)&3, 6); \
    STEPS(16*(I)+16, qq7) qq7 = LDQB(((I)+1)&3, 7); }

// ============ mega kernel: forward (0..31) | transpose (32..4127) | loss (4128..5151) ============
__global__ void __launch_bounds__(256, 1) k_mega(
        const float* __restrict__ logp, const float* __restrict__ att,
        const int* __restrict__ ilen, const int* __restrict__ olen,
        float* __restrict__ out, uint64_t* __restrict__ bits,
        float* __restrict__ partial, int* __restrict__ flags) {
    __shared__ __align__(16) float smem[16384];   // 64 KB (staging ring / transpose tile / reduce)
    int bid = blockIdx.x, tid = threadIdx.x;
    float* wsT = out + WST_OFF;

    if (bid < 32) {
        // ---------------- forward DP (one wave per batch) ----------------
        if (tid >= 64) return;
        int b = bid;
        int lane = tid;
        uint64_t* bb = bits + (size_t)b * (Ln * TB);
        const float* wbase = wsT + (size_t)b * WST_BSTRIDE;
        float* buf = smem;
        const int* cnt = flags + b * 32;
        const float negc = NEG;

        float pv0, pv1, pv2, pv3, left;
        uint32_t a0lo = 0, a0hi = 0, a1lo = 0, a1hi = 0;
        uint32_t a2lo = 0, a2hi = 0, a3lo = 0, a3hi = 0;

        // peeled t = 0: row0 = logp[b,0,0], others NEG; seed bit 0 of word 0
        {
            float lp00 = logp[(size_t)b * (Ln * Tn)];
            float n0 = (lane == 0) ? lp00 : NEG;
            float n1 = NEG, n2 = NEG, n3 = NEG;
            float sv = dpp_ror1(n3);
            a0lo |= __float_as_uint(n0 - sv) >> 31;
            a1lo |= __float_as_uint(n1 - n0) >> 31;
            a2lo |= __float_as_uint(n2 - n1) >> 31;
            a3lo |= __float_as_uint(n3 - n2) >> 31;
            left = NEG;
            pv0 = n0; pv1 = n1; pv2 = n2; pv3 = n3;
        }

        unsigned int fvA = 4, fvB = 4;
        SLOWSPIN(cnt + 0)                 // gate tile 0 (drains; once)
        FLAGLOAD(1, fvA)
        ISSUE(0)
        FLAGLOAD(2, fvB)
        ISSUE(1) ISSUE(2)                 // 48 loads + 2 flag loads in flight
        WAITV(16)                          // chunks 0,1 + both flags landed; chunk 2 flying

        float4 qq0 = LDQB(0, 0), qq1 = LDQB(0, 1), qq2 = LDQB(0, 2), qq3 = LDQB(0, 3);
        float4 qq4 = LDQB(0, 4), qq5 = LDQB(0, 5), qq6 = LDQB(0, 6), qq7 = LDQB(0, 7);

        // invariant at head: chunks <= 4m+1 landed, 4m+2 flying; fvA=flag[m+1], fvB=flag[m+2] landed
        for (int m = 0; m < 31; ++m) {
            int cb = 4 * m;
            unsigned int fnew = 4;
            if (m + 3 < 32) FLAGLOAD(m + 3, fnew)    // older than ISSUE below in vmcnt queue
            ISSUE(cb + 3) COMP16(0) WAITV(16)        // retires chunk 4m+2 (+ the flag load)
            if (fvA < 4) SLOWSPIN(cnt + m + 1)       // gate tile m+1 before its first ISSUE
            ISSUE(cb + 4) COMP16(1) WAITV(16)
            ISSUE(cb + 5) COMP16(2) WAITV(16)
            ISSUE(cb + 6) COMP16(3) WAITV(16)
            fvA = fvB; fvB = fnew;
        }
        {   // m = 31: chunks 124..127 (tile 31 gated at m=30)
            int m = 31;
            ISSUE(127) COMP16(0) WAITV(16)
            COMP16(1) WAITV(0)             // drain chunk 127 before its rows are prefetched
            COMP16(2)
            COMP16(3)                      // j>=8 prefetches read stale buffer 0: never consumed
        }
    } else if (bid < 32 + 4096) {
        // -------- transpose logp[b][l][t] -> wsT[b][t-1][l], tt-major; stride-65 tile --------
        const int TS = 65;                 // odd stride: ~2-way banks both passes
        int bid2 = bid - 32;
        int tt = bid2 >> 7;                // early blocks produce early t
        int rest = bid2 & 127;
        int b = rest >> 2;
        int lt = rest & 3;
        float* tile = smem;                // [64][65]
        const float* src = logp + ((size_t)b * Ln + lt * 64) * Tn + (size_t)tt * 64;
        int lr = tid >> 4, tc4 = (tid & 15) * 4;
        #pragma unroll
        for (int pass = 0; pass < 4; ++pass) {
            int l_loc = pass * 16 + lr;
            float4 v = *(const float4*)(src + (size_t)l_loc * Tn + tc4);
            tile[l_loc * TS + tc4 + 0] = v.x;
            tile[l_loc * TS + tc4 + 1] = v.y;
            tile[l_loc * TS + tc4 + 2] = v.z;
            tile[l_loc * TS + tc4 + 3] = v.w;
        }
        __syncthreads();
        float* dst = wsT + (size_t)b * WST_BSTRIDE + lt * 64;
        #pragma unroll
        for (int pass = 0; pass < 4; ++pass) {
            int t_loc = pass * 16 + lr;
            float4 v;
            v.x = tile[(tc4 + 0) * TS + t_loc];
            v.y = tile[(tc4 + 1) * TS + t_loc];
            v.z = tile[(tc4 + 2) * TS + t_loc];
            v.w = tile[(tc4 + 3) * TS + t_loc];
            int tg = tt * 64 + t_loc;
            if (tg >= 1) *(float4*)(dst + (size_t)(tg - 1) * Ln + tc4) = v;
        }
        __syncthreads();                   // all this block's stores drained
        if (tid == 0)                      // release: writeback + publish
            __hip_atomic_fetch_add(&flags[b * 32 + tt], 1,
                                   __ATOMIC_RELEASE, __HIP_MEMORY_SCOPE_AGENT);
    } else {
        // ---------------- guided-attention loss partials (free-riders, no sync) ----------------
        const int N4 = Bn * Tn * Ln / 4;
        int j = bid - 4128;
        int idx = j * 256 + tid;
        int stride = 1024 * 256;
        float acc = 0.f;
        for (int v = idx; v < N4; v += stride) {
            int flat = v << 2;                   // att is (B, T, L)
            int b  = flat >> 19;
            int t  = (flat >> 8) & (Tn - 1);
            int l0 = flat & (Ln - 1);
            int ili = ilen[b];
            int oli = olen[b];
            if (t >= oli) continue;
            float il = (float)ili, ol = (float)oli;
            float tf = (float)t / ol;
            float4 a = reinterpret_cast<const float4*>(att)[v];
            #pragma unroll
            for (int c = 0; c < 4; ++c) {
                int l = l0 + c;
                float av = (c == 0) ? a.x : (c == 1) ? a.y : (c == 2) ? a.z : a.w;
                if (l < ili) {
                    float d = (float)l / il - tf;
                    acc += (1.f - __expf(-d * d * 3.125f)) * av;
                }
            }
        }
        for (int off = 32; off > 0; off >>= 1) acc += __shfl_down(acc, off, 64);
        float* sw = smem;
        if ((tid & 63) == 0) sw[tid >> 6] = acc;
        __syncthreads();
        if (tid == 0) partial[j] = (sw[0] + sw[1]) + (sw[2] + sw[3]);
    }
}

// ---------------- backtrack: LDS bits, 4-deep window walk -> per-row extents ----------------
__global__ void __launch_bounds__(64) k_backtrack3(const uint64_t* __restrict__ bits,
                                                   const int* __restrict__ ilen,
                                                   const int* __restrict__ olen,
                                                   int2* __restrict__ ext) {
    __shared__ uint64_t sb[Ln * TB];   // 64 KB
    int b = blockIdx.x, lane = threadIdx.x;
    #pragma unroll
    for (int i = 0; i < 4; ++i) ext[b * Ln + i * 64 + lane] = make_int2(1, 0);  // empty
    const ulonglong2* g = (const ulonglong2*)(bits + (size_t)b * (Ln * TB));
    ulonglong2* s2 = (ulonglong2*)sb;
    #pragma unroll
    for (int i = 0; i < 64; ++i) s2[i * 64 + lane] = g[i * 64 + lane];
    __syncthreads();
    if (lane != 0) return;

    int tl = ilen[b], ml = olen[b];
    int2* eb = ext + b * Ln;
    int r = tl - 1, hi = ml - 1, p = ml - 2;
    if (p < 0) { eb[r] = make_int2(0, hi); return; }
    int c = p >> 6;
    uint64_t w0 = sb[r * TB + c];
    uint64_t w1 = sb[(r > 0 ? r - 1 : 0) * TB + c];
    uint64_t w2 = sb[(r > 1 ? r - 2 : 0) * TB + c];
    uint64_t w3 = sb[(r > 2 ? r - 3 : 0) * TB + c];
    int vd = 3;
    while (true) {
        int pb = p & 63;
        uint64_t mask = (pb == 63) ? ~0ull : ((1ull << (pb + 1)) - 1ull);
        uint64_t m = w0 & mask;
        if (m == 0) {
            p = (p & ~63) - 1;
            if (p < 0) { eb[r] = make_int2(0, hi); break; }
            c = p >> 6;
            w0 = sb[r * TB + c];
            w1 = sb[(r > 0 ? r - 1 : 0) * TB + c];
            w2 = sb[(r > 1 ? r - 2 : 0) * TB + c];
            w3 = sb[(r > 2 ? r - 3 : 0) * TB + c];
            vd = 3;
        } else {
            int q = 63 - __builtin_clzll(m);
            int tq = (p & ~63) + q;
            eb[r] = make_int2(tq + 1, hi);
            r -= 1;
            if (r < 0) break;                   // saturation: remaining columns zero
            hi = tq;
            p = tq - 1;
            if (p < 0) { eb[r] = make_int2(0, hi); break; }
            w0 = w1; w1 = w2; w2 = w3; vd -= 1;
            int nc = p >> 6;
            if (nc != c || vd == 0) {
                c = nc;
                w0 = sb[r * TB + c];
                w1 = sb[(r > 0 ? r - 1 : 0) * TB + c];
                w2 = sb[(r > 1 ? r - 2 : 0) * TB + c];
                w3 = sb[(r > 2 ? r - 3 : 0) * TB + c];
                vd = 3;
            }
        }
    }
}

// ---------------- aligned-float4 fill from extents + fused final loss reduce ----------------
__global__ void k_fill(const int2* __restrict__ ext, const float* __restrict__ partial,
                       const int* __restrict__ olen, float* __restrict__ out) {
    const int NG = (Bn * Ln * Tn) / 4;          // 4,194,304 aligned float4 groups
    int idx = blockIdx.x * blockDim.x + threadIdx.x;
    int stride = gridDim.x * blockDim.x;
    for (int i = idx; i < NG; i += stride) {
        if (i == 0) {
            int2 e = ext[0];                     // out[1..3] = align f=0..2 (row 0)
            out[1] = (0 >= e.x && 0 <= e.y) ? 1.f : 0.f;
            out[2] = (1 >= e.x && 1 <= e.y) ? 1.f : 0.f;
            out[3] = (2 >= e.x && 2 <= e.y) ? 1.f : 0.f;
            int2 el = ext[Bn * Ln - 1];          // last element: row 8191, t=2047
            out[(size_t)Bn * Ln * Tn] = (2047 >= el.x && 2047 <= el.y) ? 1.f : 0.f;
            continue;
        }
        int f0 = 4 * i - 1;                      // align flat index of out[4i]
        int r0 = f0 >> 11;
        int t0 = f0 & 2047;
        int2 e0 = ext[r0];
        float4 v;
        if (t0 != 2047) {                        // all 4 in row r0
            v.x = (t0     >= e0.x && t0     <= e0.y) ? 1.f : 0.f;
            v.y = (t0 + 1 >= e0.x && t0 + 1 <= e0.y) ? 1.f : 0.f;
            v.z = (t0 + 2 >= e0.x && t0 + 2 <= e0.y) ? 1.f : 0.f;
            v.w = (t0 + 3 >= e0.x && t0 + 3 <= e0.y) ? 1.f : 0.f;
        } else {                                 // crosses into row r0+1 (t=0,1,2)
            int2 e1 = ext[r0 + 1];
            v.x = (2047 >= e0.x && 2047 <= e0.y) ? 1.f : 0.f;
            v.y = (0 >= e1.x && 0 <= e1.y) ? 1.f : 0.f;
            v.z = (1 >= e1.x && 1 <= e1.y) ? 1.f : 0.f;
            v.w = (2 >= e1.x && 2 <= e1.y) ? 1.f : 0.f;
        }
        *reinterpret_cast<float4*>(out + (size_t)4 * i) = v;
    }
    if (blockIdx.x == 0) {                       // fused deterministic loss reduce
        int tid = threadIdx.x;
        float acc = 0.f;
        for (int i = tid; i < 1024; i += 256) acc += partial[i];
        for (int off = 32; off > 0; off >>= 1) acc += __shfl_down(acc, off, 64);
        __shared__ float sw[4];
        if ((tid & 63) == 0) sw[tid >> 6] = acc;
        __syncthreads();
        if (tid == 0) {
            float tot = (sw[0] + sw[1]) + (sw[2] + sw[3]);
            int so = 0;
            for (int i = 0; i < Bn; ++i) so += olen[i];
            out[0] = tot / (float)so;
        }
    }
}

extern "C" void kernel_launch(void* const* d_in, const int* in_sizes, int n_in,
                              void* d_out, int out_size, void* d_ws, size_t ws_size,
                              hipStream_t stream) {
    const float* logp = (const float*)d_in[0];
    const float* att  = (const float*)d_in[1];
    const int* tlen   = (const int*)d_in[2];
    const int* mlen   = (const int*)d_in[3];
    float* out = (float*)d_out;
    uint64_t* bits = (uint64_t*)d_ws;                            // 2 MB
    float* partial = (float*)((char*)d_ws + 2097152);            // 4 KB
    int2* ext = (int2*)((char*)d_ws + 2101248);                  // 64 KB
    int* flags = (int*)((char*)d_ws + 2166784);                  // 1024 ints

    // 0) zero the producer/consumer flags (graph-capture legal)
    hipMemsetAsync(flags, 0, 1024 * sizeof(int), stream);
    // 1) mega kernel: forward DP overlapped with transpose producers + loss free-riders
    k_mega<<<5152, 256, 0, stream>>>(logp, att, tlen, mlen, out, bits, partial, flags);
    // 2) backtrack -> per-row run extents
    k_backtrack3<<<Bn, 64, 0, stream>>>(bits, tlen, mlen, ext);
    // 3) write full 0/1 output from extents + final loss reduce (overwrites scratch)
    k_fill<<<2048, 256, 0, stream>>>(ext, partial, mlen, out);
}

// Round 8
// 164.626 us; speedup vs baseline: 2.0977x; 1.9237x over previous
//
#include <hip/hip_runtime.h>
#include <cstdint>

#define NEG (-1e12f)
constexpr int Bn = 32, Ln = 256, Tn = 2048;
constexpr int TB = Tn / 64;                 // 32 uint64 words of t-bits per text row

// d_ws layout (bytes):
//   bits    @ 0       : 32*256*32*8 = 2,097,152
//   partial @ 2097152 : 1024 floats (4 KB)
//   ext     @ 2101248 : 8192 int2  (64 KB)

// lane i <- lane (i-1)&63  (wave_ror:1) : torch-wrap neighbor for the bit compare
__device__ inline float dpp_ror1(float x) {
    int xi = __float_as_int(x);
    return __int_as_float(__builtin_amdgcn_update_dpp(xi, xi, 0x13C, 0xF, 0xF, false));
}
// lane i <- lane i-1, lane 0 <- old  (wave_shr:1) : DP 'left' input directly
__device__ inline float dpp_shr1(float x, float old) {
    return __int_as_float(__builtin_amdgcn_update_dpp(
        __float_as_int(old), __float_as_int(x), 0x138, 0xF, 0xF, false));
}

__device__ inline uint32_t lds_off(const void* p) {
    return (uint32_t)(uintptr_t)(__attribute__((address_space(3))) const void*)p;
}

// raw barrier: NO implicit vmcnt drain (producers' global loads stay in flight)
#define BARRIER() { asm volatile("" ::: "memory"); \
                    __builtin_amdgcn_s_barrier(); \
                    asm volatile("" ::: "memory"); }

// forced LDS read into an asm-tied float4 slot; OFF is a byte-offset string literal
#define DSR(DST, VA, OFF) asm volatile("ds_read_b128 %0, %1 offset:" OFF \
                                       : "=&v"(DST) : "v"(VA));
// consume gate: oldest of 8 outstanding ds_reads landed; fence non-asm hoisting (rule #18)
#define W7 { asm volatile("s_waitcnt lgkmcnt(7)"); __builtin_amdgcn_sched_barrier(0); }

// S = t - 64m (1..64) compile-time; Q = slot float4 for this step
#define STEPS(S, Q) { \
    float c3 = fmaxf(pv3, pv2) + (Q).w; \
    float c2 = fmaxf(pv2, pv1) + (Q).z; \
    float c1 = fmaxf(pv1, pv0) + (Q).y; \
    float c0 = fmaxf(pv0, left) + (Q).x; \
    float sv = dpp_ror1(c3); \
    left = dpp_shr1(c3, negc); \
    uint32_t e0 = __float_as_uint(c0 - sv) >> 31; \
    uint32_t e1 = __float_as_uint(c1 - c0) >> 31; \
    uint32_t e2 = __float_as_uint(c2 - c1) >> 31; \
    uint32_t e3 = __float_as_uint(c3 - c2) >> 31; \
    if (((S) & 32) == 0) { \
        a0lo |= e0 << ((S) & 31); a1lo |= e1 << ((S) & 31); \
        a2lo |= e2 << ((S) & 31); a3lo |= e3 << ((S) & 31); \
    } else { \
        a0hi |= e0 << ((S) & 31); a1hi |= e1 << ((S) & 31); \
        a2hi |= e2 << ((S) & 31); a3hi |= e3 << ((S) & 31); \
    } \
    if ((S) == 63) { \
        bb[(size_t)(4 * lane + 0) * TB + m] = ((uint64_t)a0hi << 32) | a0lo; \
        bb[(size_t)(4 * lane + 1) * TB + m] = ((uint64_t)a1hi << 32) | a1lo; \
        bb[(size_t)(4 * lane + 2) * TB + m] = ((uint64_t)a2hi << 32) | a2lo; \
        bb[(size_t)(4 * lane + 3) * TB + m] = ((uint64_t)a3hi << 32) | a3lo; \
        a0lo = a0hi = a1lo = a1hi = a2lo = a2hi = a3lo = a3hi = 0; \
    } \
    pv0 = c0; pv1 = c1; pv2 = c2; pv3 = c3; }

// 16 DP steps of sub-chunk I. Ring buffer = VA; next chunk's buffer = VB.
// Slot rotation: step s consumes qq[(s-1)&7], then reissues that slot for step s+8.
// Row byte offsets: row r of a buffer = r*1024.
#define COMP16X(I, VA, VB) { \
    W7 STEPS(16*(I)+ 1, qq0) DSR(qq0, VA, "9216") \
    W7 STEPS(16*(I)+ 2, qq1) DSR(qq1, VA, "10240") \
    W7 STEPS(16*(I)+ 3, qq2) DSR(qq2, VA, "11264") \
    W7 STEPS(16*(I)+ 4, qq3) DSR(qq3, VA, "12288") \
    W7 STEPS(16*(I)+ 5, qq4) DSR(qq4, VA, "13312") \
    W7 STEPS(16*(I)+ 6, qq5) DSR(qq5, VA, "14336") \
    W7 STEPS(16*(I)+ 7, qq6) DSR(qq6, VA, "15360") \
    W7 STEPS(16*(I)+ 8, qq7) DSR(qq7, VB, "0") \
    W7 STEPS(16*(I)+ 9, qq0) DSR(qq0, VB, "1024") \
    W7 STEPS(16*(I)+10, qq1) DSR(qq1, VB, "2048") \
    W7 STEPS(16*(I)+11, qq2) DSR(qq2, VB, "3072") \
    W7 STEPS(16*(I)+12, qq3) DSR(qq3, VB, "4096") \
    W7 STEPS(16*(I)+13, qq4) DSR(qq4, VB, "5120") \
    W7 STEPS(16*(I)+14, qq5) DSR(qq5, VB, "6144") \
    W7 STEPS(16*(I)+15, qq6) DSR(qq6, VB, "7168") \
    W7 STEPS(16*(I)+16, qq7) DSR(qq7, VB, "8192") \
}

// producer reg-staged load of chunk P (t = 16P..16P+15), 6 float4 per thread
#define PLOAD(P) { \
    xh0 = *(const float4*)(pr0 + 16 * (P)); \
    xh1 = *(const float4*)(pr1 + 16 * (P)); \
    xh2 = *(const float4*)(pr2 + 16 * (P)); \
    xh3 = *(const float4*)(pr3 + 16 * (P)); \
    xh4 = *(const float4*)(pr4 + 16 * (P)); \
    if (six) xh5 = *(const float4*)(pr5 + 16 * (P)); }

#define PW1(XH, CC) { float* rq = rr + (CC); \
    rq[0] = (XH).x; rq[256] = (XH).y; rq[512] = (XH).z; rq[768] = (XH).w; }

#define PWRITE(P) { \
    float* rr = smem + ((P) & 3) * 4096; \
    PW1(xh0, c0) PW1(xh1, c1) PW1(xh2, c2) PW1(xh3, c3) PW1(xh4, c4) \
    if (six) PW1(xh5, c5) }

// ============ mega kernel: blocks 0..31 forward(+staging) | 32..1055 loss ============
__global__ void __launch_bounds__(256, 1) k_mega(
        const float* __restrict__ logp, const float* __restrict__ att,
        const int* __restrict__ ilen, const int* __restrict__ olen,
        uint64_t* __restrict__ bits, float* __restrict__ partial) {
    __shared__ __align__(16) float smem[16384];   // 64 KB: 4 ring buffers x 16 t x 256 l
    int bid = blockIdx.x, tid = threadIdx.x;

    if (bid < 32) {
        int b = bid;
        if (tid < 64) {
            // ---------------- DP consumer wave ----------------
            __builtin_amdgcn_s_setprio(1);
            int lane = tid;
            uint64_t* bb = bits + (size_t)b * (Ln * TB);
            const float negc = NEG;
            uint32_t lb = lds_off(smem) + (uint32_t)(lane * 16);
            uint32_t va0 = lb, va1 = lb + 16384, va2 = lb + 32768, va3 = lb + 49152;

            float pv0, pv1, pv2, pv3, left;
            uint32_t a0lo = 0, a0hi = 0, a1lo = 0, a1hi = 0;
            uint32_t a2lo = 0, a2hi = 0, a3lo = 0, a3hi = 0;

            // peeled t = 0: row0 = logp[b,0,0], others NEG; seed bit 0 of word 0
            {
                float lp00 = logp[(size_t)b * (Ln * Tn)];
                float n0 = (lane == 0) ? lp00 : NEG;
                float n1 = NEG, n2 = NEG, n3 = NEG;
                float sv = dpp_ror1(n3);
                a0lo |= __float_as_uint(n0 - sv) >> 31;
                a1lo |= __float_as_uint(n1 - n0) >> 31;
                a2lo |= __float_as_uint(n2 - n1) >> 31;
                a3lo |= __float_as_uint(n3 - n2) >> 31;
                left = NEG;
                pv0 = n0; pv1 = n1; pv2 = n2; pv3 = n3;
            }

            BARRIER();                         // chunks 0,1 produced; chunk 2 staged in regs
            float4 qq0, qq1, qq2, qq3, qq4, qq5, qq6, qq7;
            DSR(qq0, va0, "1024") DSR(qq1, va0, "2048")   // rows 1..8 of chunk 0
            DSR(qq2, va0, "3072") DSR(qq3, va0, "4096")
            DSR(qq4, va0, "5120") DSR(qq5, va0, "6144")
            DSR(qq6, va0, "7168") DSR(qq7, va0, "8192")

            for (int m = 0; m < 32; ++m) {
                COMP16X(0, va0, va1) BARRIER()
                COMP16X(1, va1, va2) BARRIER()
                COMP16X(2, va2, va3) BARRIER()
                COMP16X(3, va3, va0) BARRIER()
            }
        } else {
            // ---------------- producer waves (stage logp -> LDS ring, transposed) ----------------
            int tid2 = tid - 64;                         // 0..191
            bool six = (tid2 < 64);                      // wave-uniform extra element
            const float* lpb = logp + (size_t)b * (Ln * Tn);
            int v0 = tid2, v1 = tid2 + 192, v2 = tid2 + 384,
                v3 = tid2 + 576, v4 = tid2 + 768, v5 = tid2 + 960;
            const float* pr0 = lpb + (size_t)(v0 >> 2) * Tn + 4 * (v0 & 3);
            const float* pr1 = lpb + (size_t)(v1 >> 2) * Tn + 4 * (v1 & 3);
            const float* pr2 = lpb + (size_t)(v2 >> 2) * Tn + 4 * (v2 & 3);
            const float* pr3 = lpb + (size_t)(v3 >> 2) * Tn + 4 * (v3 & 3);
            const float* pr4 = lpb + (size_t)(v4 >> 2) * Tn + 4 * (v4 & 3);
            const float* pr5 = lpb + (size_t)(v5 >> 2) * Tn + 4 * (v5 & 3);
            int c0 = (4 * (v0 & 3)) * 256 + (v0 >> 2);
            int c1 = (4 * (v1 & 3)) * 256 + (v1 >> 2);
            int c2 = (4 * (v2 & 3)) * 256 + (v2 >> 2);
            int c3 = (4 * (v3 & 3)) * 256 + (v3 >> 2);
            int c4 = (4 * (v4 & 3)) * 256 + (v4 >> 2);
            int c5 = (4 * (v5 & 3)) * 256 + (v5 >> 2);
            float4 xh0, xh1, xh2, xh3, xh4, xh5;

            PLOAD(0) PWRITE(0)                 // prologue: chunks 0,1 in LDS; chunk 2 in regs
            PLOAD(1) PWRITE(1)
            PLOAD(2)
            asm volatile("s_waitcnt lgkmcnt(0)" ::: "memory");
            BARRIER();

            for (int k = 0; k < 128; ++k) {
                if (k <= 125) PWRITE(k + 2)    // write chunk staged last iteration
                if (k <= 124) PLOAD(k + 3)     // loads span the barrier (raw s_barrier)
                asm volatile("s_waitcnt lgkmcnt(0)" ::: "memory");
                BARRIER();
            }
        }
    } else {
        // ---------------- guided-attention loss partials (independent blocks) ----------------
        const int N4 = Bn * Tn * Ln / 4;
        int j = bid - 32;
        int idx = j * 256 + tid;
        int stride = 1024 * 256;
        float acc = 0.f;
        for (int v = idx; v < N4; v += stride) {
            int flat = v << 2;                   // att is (B, T, L)
            int b  = flat >> 19;
            int t  = (flat >> 8) & (Tn - 1);
            int l0 = flat & (Ln - 1);
            int ili = ilen[b];
            int oli = olen[b];
            if (t >= oli) continue;
            float il = (float)ili, ol = (float)oli;
            float tf = (float)t / ol;
            float4 a = reinterpret_cast<const float4*>(att)[v];
            #pragma unroll
            for (int c = 0; c < 4; ++c) {
                int l = l0 + c;
                float av = (c == 0) ? a.x : (c == 1) ? a.y : (c == 2) ? a.z : a.w;
                if (l < ili) {
                    float d = (float)l / il - tf;
                    acc += (1.f - __expf(-d * d * 3.125f)) * av;
                }
            }
        }
        for (int off = 32; off > 0; off >>= 1) acc += __shfl_down(acc, off, 64);
        float* sw = smem;
        if ((tid & 63) == 0) sw[tid >> 6] = acc;
        __syncthreads();
        if (tid == 0) partial[j] = (sw[0] + sw[1]) + (sw[2] + sw[3]);
    }
}

// ---------------- backtrack: LDS bits, 4-deep window walk -> per-row extents ----------------
__global__ void __launch_bounds__(64) k_backtrack3(const uint64_t* __restrict__ bits,
                                                   const int* __restrict__ ilen,
                                                   const int* __restrict__ olen,
                                                   int2* __restrict__ ext) {
    __shared__ uint64_t sb[Ln * TB];   // 64 KB
    int b = blockIdx.x, lane = threadIdx.x;
    #pragma unroll
    for (int i = 0; i < 4; ++i) ext[b * Ln + i * 64 + lane] = make_int2(1, 0);  // empty
    const ulonglong2* g = (const ulonglong2*)(bits + (size_t)b * (Ln * TB));
    ulonglong2* s2 = (ulonglong2*)sb;
    #pragma unroll
    for (int i = 0; i < 64; ++i) s2[i * 64 + lane] = g[i * 64 + lane];
    __syncthreads();
    if (lane != 0) return;

    int tl = ilen[b], ml = olen[b];
    int2* eb = ext + b * Ln;
    int r = tl - 1, hi = ml - 1, p = ml - 2;
    if (p < 0) { eb[r] = make_int2(0, hi); return; }
    int c = p >> 6;
    uint64_t w0 = sb[r * TB + c];
    uint64_t w1 = sb[(r > 0 ? r - 1 : 0) * TB + c];
    uint64_t w2 = sb[(r > 1 ? r - 2 : 0) * TB + c];
    uint64_t w3 = sb[(r > 2 ? r - 3 : 0) * TB + c];
    int vd = 3;
    while (true) {
        int pb = p & 63;
        uint64_t mask = (pb == 63) ? ~0ull : ((1ull << (pb + 1)) - 1ull);
        uint64_t m = w0 & mask;
        if (m == 0) {
            p = (p & ~63) - 1;
            if (p < 0) { eb[r] = make_int2(0, hi); break; }
            c = p >> 6;
            w0 = sb[r * TB + c];
            w1 = sb[(r > 0 ? r - 1 : 0) * TB + c];
            w2 = sb[(r > 1 ? r - 2 : 0) * TB + c];
            w3 = sb[(r > 2 ? r - 3 : 0) * TB + c];
            vd = 3;
        } else {
            int q = 63 - __builtin_clzll(m);
            int tq = (p & ~63) + q;
            eb[r] = make_int2(tq + 1, hi);
            r -= 1;
            if (r < 0) break;                   // saturation: remaining columns zero
            hi = tq;
            p = tq - 1;
            if (p < 0) { eb[r] = make_int2(0, hi); break; }
            w0 = w1; w1 = w2; w2 = w3; vd -= 1;
            int nc = p >> 6;
            if (nc != c || vd == 0) {
                c = nc;
                w0 = sb[r * TB + c];
                w1 = sb[(r > 0 ? r - 1 : 0) * TB + c];
                w2 = sb[(r > 1 ? r - 2 : 0) * TB + c];
                w3 = sb[(r > 2 ? r - 3 : 0) * TB + c];
                vd = 3;
            }
        }
    }
}

// ---------------- aligned-float4 fill from extents + fused final loss reduce ----------------
__global__ void k_fill(const int2* __restrict__ ext, const float* __restrict__ partial,
                       const int* __restrict__ olen, float* __restrict__ out) {
    const int NG = (Bn * Ln * Tn) / 4;          // 4,194,304 aligned float4 groups
    int idx = blockIdx.x * blockDim.x + threadIdx.x;
    int stride = gridDim.x * blockDim.x;
    for (int i = idx; i < NG; i += stride) {
        if (i == 0) {
            int2 e = ext[0];                     // out[1..3] = align f=0..2 (row 0)
            out[1] = (0 >= e.x && 0 <= e.y) ? 1.f : 0.f;
            out[2] = (1 >= e.x && 1 <= e.y) ? 1.f : 0.f;
            out[3] = (2 >= e.x && 2 <= e.y) ? 1.f : 0.f;
            int2 el = ext[Bn * Ln - 1];          // last element: row 8191, t=2047
            out[(size_t)Bn * Ln * Tn] = (2047 >= el.x && 2047 <= el.y) ? 1.f : 0.f;
            continue;
        }
        int f0 = 4 * i - 1;                      // align flat index of out[4i]
        int r0 = f0 >> 11;
        int t0 = f0 & 2047;
        int2 e0 = ext[r0];
        float4 v;
        if (t0 != 2047) {                        // all 4 in row r0
            v.x = (t0     >= e0.x && t0     <= e0.y) ? 1.f : 0.f;
            v.y = (t0 + 1 >= e0.x && t0 + 1 <= e0.y) ? 1.f : 0.f;
            v.z = (t0 + 2 >= e0.x && t0 + 2 <= e0.y) ? 1.f : 0.f;
            v.w = (t0 + 3 >= e0.x && t0 + 3 <= e0.y) ? 1.f : 0.f;
        } else {                                 // crosses into row r0+1 (t=0,1,2)
            int2 e1 = ext[r0 + 1];
            v.x = (2047 >= e0.x && 2047 <= e0.y) ? 1.f : 0.f;
            v.y = (0 >= e1.x && 0 <= e1.y) ? 1.f : 0.f;
            v.z = (1 >= e1.x && 1 <= e1.y) ? 1.f : 0.f;
            v.w = (2 >= e1.x && 2 <= e1.y) ? 1.f : 0.f;
        }
        *reinterpret_cast<float4*>(out + (size_t)4 * i) = v;
    }
    if (blockIdx.x == 0) {                       // fused deterministic loss reduce
        int tid = threadIdx.x;
        float acc = 0.f;
        for (int i = tid; i < 1024; i += 256) acc += partial[i];
        for (int off = 32; off > 0; off >>= 1) acc += __shfl_down(acc, off, 64);
        __shared__ float sw[4];
        if ((tid & 63) == 0) sw[tid >> 6] = acc;
        __syncthreads();
        if (tid == 0) {
            float tot = (sw[0] + sw[1]) + (sw[2] + sw[3]);
            int so = 0;
            for (int i = 0; i < Bn; ++i) so += olen[i];
            out[0] = tot / (float)so;
        }
    }
}

extern "C" void kernel_launch(void* const* d_in, const int* in_sizes, int n_in,
                              void* d_out, int out_size, void* d_ws, size_t ws_size,
                              hipStream_t stream) {
    const float* logp = (const float*)d_in[0];
    const float* att  = (const float*)d_in[1];
    const int* tlen   = (const int*)d_in[2];
    const int* mlen   = (const int*)d_in[3];
    float* out = (float*)d_out;
    uint64_t* bits = (uint64_t*)d_ws;                            // 2 MB
    float* partial = (float*)((char*)d_ws + 2097152);            // 4 KB
    int2* ext = (int2*)((char*)d_ws + 2101248);                  // 64 KB

    // 1) mega: forward DP (in-block staging waves) + concurrent loss partials
    k_mega<<<32 + 1024, 256, 0, stream>>>(logp, att, tlen, mlen, bits, partial);
    // 2) backtrack -> per-row run extents
    k_backtrack3<<<Bn, 64, 0, stream>>>(bits, tlen, mlen, ext);
    // 3) write full 0/1 output from extents + final loss reduce
    k_fill<<<2048, 256, 0, stream>>>(ext, partial, mlen, out);
}